// Round 7
// baseline (448.325 us; speedup 1.0000x reference)
//
#include <hip/hip_runtime.h>

// LSTM enc(20, in=2) + dec(30, in=h) fused, HID=64, f32 I/O.
// Gates-transposed MFMA recurrence, v_mfma_f32_16x16x32_f16 (K=32).
//   D[n][m] = sum_k W[n][k] h[m][k]; C/D: col=l&15, row=4*(l>>4)+r (m89,
//   dtype-independent).
// k-relabeling: BOTH operands packed with f(q,tg,e) = 32q + 8tg + e
// (a bijection over [0,64); any f applied to A and B identically leaves
// D unchanged). So A-frag q = 8 CONTIGUOUS floats W[n][32q+8tg .. +7],
// and B-frag q = h[32q+8tg .. +7] = one b128 from identity-layout LDS.
// Wave w owns hidden j in [16w,16w+16). Cross-wave h exchange through a
// double-buffered XOR-swizzled LDS tile, 1 barrier/step:
//   write: wave w lane(m,tg) stores jb=4w+tg at slot jb^(m&14) (free)
//   read:  b128 at slot (8q+2tg)^(m&14) -> h[32q+8tg..+7] (free)
// Output path: Linear(h) via deferred MFMA (wave0=tile0, wave1=tile1) on the
// b-frags read at iteration end; LA-frag same f-pack (single f16, NOT scaled).
// TWO batch tiles per block (32 batch) share weight VGPRs and the barrier.
//
// R6: scale-folded gates (exp2 domain) + single-rcp fused cell math:
//   7 trans/h (5 exp2 + 2 rcp).  886->830 rocprof; VALU 64->59.
// R7: pk-f32 vectorized cell math + unroll 2.  VALU 59->55.7.
// R8: bf16 -> f16 (f16-RNE h, no h-lo): 48 -> 32 MFMAs/step.  rocprof
//   850->655, wall 709->570; absmax UNCHANGED 2.4e-4.
// R9: single f16-RNE W (drop W-lo): 32 -> 16 MFMAs/step.  rocprof 655->548,
//   wall 570->468, MfmaUtil 18.1 (predicted 18), absmax STILL 2.4e-4.
// R10 FAILED: (256,4) clamped arch VGPRs to 64 -> massive spill (1.5 GB
//   scratch), wall 620.  Occupancy DID rise to 43% -> residency is the
//   limiter, but live state exceeds the 4-wave budget.
// R11: (256,3): allocator clamps to 84 VGPR (NOT 512/3=170!), occ 33%,
//   wall 468->437, but still ~278 MB scratch (FETCH 83M/WRITE 195M):
//   ~1-2 f32 spill slots in the hot loop.  Empirical demand target: <=84.
// R12 (this round): tile-SEQUENTIAL step body.  Old order ran all 16
//   MFMAs (a0+a1 = 32 acc VGPRs live) before the cellacts; new order is
//   MFMA(tile0) -> cellact0 -> MFMA(tile1) -> cellact1, halving peak acc
//   pressure (and cellact0's trans burst overlaps tile1's MFMAs).
//   Demand ~108-24 ~= 84 = the clamp -> hot-loop spills vanish at 3
//   blocks/CU.  Pass/fail: FETCH back to ~11k KB, WRITE ~31k KB.

#define LOG2E 1.44269504088896340736f
#define TWO_LOG2E 2.88539008177792681472f

typedef __attribute__((ext_vector_type(4))) short short4v;
typedef __attribute__((ext_vector_type(4))) float float4v;
typedef _Float16 __attribute__((ext_vector_type(8))) half8v;

#if defined(__HIP_DEVICE_COMPILE__)
#define MFMAH(a, b, c) __builtin_amdgcn_mfma_f32_16x16x32_f16((a), (b), (c), 0, 0, 0)
#else
#define MFMAH(a, b, c) (c)
#endif

__device__ __forceinline__ float4v exp2v4(float4v x) {
  float4v r;
  r[0] = __builtin_amdgcn_exp2f(x[0]);
  r[1] = __builtin_amdgcn_exp2f(x[1]);
  r[2] = __builtin_amdgcn_exp2f(x[2]);
  r[3] = __builtin_amdgcn_exp2f(x[3]);
  return r;
}
__device__ __forceinline__ float4v rcpv4(float4v x) {
  float4v r;
  r[0] = __builtin_amdgcn_rcpf(x[0]);
  r[1] = __builtin_amdgcn_rcpf(x[1]);
  r[2] = __builtin_amdgcn_rcpf(x[2]);
  r[3] = __builtin_amdgcn_rcpf(x[3]);
  return r;
}

// Fused LSTM cell update on 4 rows (pk-f32).  a[0..3] = gates i,f,g,o
// PRE-SCALED (i,f,o by -log2e; g by 2log2e).  c holds 2log2e*cell.
// Emits h as 4 f16 (RNE) bit-patterns.
__device__ __forceinline__ void cellact(const float4v* a, float4v& c,
                                        short4v& hh) {
  const float4v one = {1.f, 1.f, 1.f, 1.f};
  const float4v clo = {-36.f, -36.f, -36.f, -36.f};
  const float4v chi = {36.f, 36.f, 36.f, 36.f};
  float4v Ei = exp2v4(a[0]);                    // e^{-i}
  float4v Ef = exp2v4(a[1]);                    // e^{-f}
  float4v Eg = exp2v4(a[2]);                    // e^{2g}
  float4v Eo = exp2v4(a[3]);                    // e^{-o}
  float4v t1 = one + Ei;
  float4v t2 = one + Eg;
  float4v t3 = one + Ef;
  float4v t4s = Eg * TWO_LOG2E - TWO_LOG2E;     // 2log2e*(Eg-1), pk_fma
  float4v P = t1 * t2;
  float4v num = c * P + t4s * t3;               // pk_mul + pk_fma
  float4v cs = num * rcpv4(P * t3);             // 2log2e * c_new
  c = cs;
  float4v cl = __builtin_elementwise_min(__builtin_elementwise_max(cs, clo), chi);
  float4v Ec = exp2v4(cl);                      // e^{2*c_new}
  float4v h = (Ec - one) * rcpv4((one + Ec) * (one + Eo));
#pragma unroll
  for (int r = 0; r < 4; ++r) {
    _Float16 hf = (_Float16)h[r];               // v_cvt_f16_f32 (RNE)
    hh[r] = (short)__builtin_bit_cast(unsigned short, hf);
  }
}

__global__ __launch_bounds__(256, 3) void lstm_fused(
    const float* __restrict__ x,     // [B][20][2]
    const float* __restrict__ eWih,  // [256][2]
    const float* __restrict__ eWhh,  // [256][64]
    const float* __restrict__ ebih,  // [256]
    const float* __restrict__ ebhh,  // [256]
    const float* __restrict__ dWih,  // [256][64]
    const float* __restrict__ dWhh,  // [256][64]
    const float* __restrict__ dbih,  // [256]
    const float* __restrict__ dbhh,  // [256]
    const float* __restrict__ linW,  // [2][64]
    const float* __restrict__ linb,  // [2]
    float* __restrict__ out,         // [B][30][2]
    int B) {
  const int tid = threadIdx.x;
  const int w   = tid >> 6;    // wave: hidden block [16w, 16w+16)
  const int l   = tid & 63;
  const int m   = l & 15;      // batch col within tile
  const int tg  = l >> 4;
  const int msk = m & 14;
  const int wslot = (((w << 2) | tg) ^ msk) << 2;   // halfword off, b64 write
  const int bg  = blockIdx.x * 32;

  __shared__ __align__(16) unsigned short Hh[2][32][64];  // f16 bits
  __shared__ __align__(16) float Xs[32][42];   // stride 42: 2-way max (free)

  // ---- stage x: x[bg+mm][st][c] -> Xs[mm][2*st+c] ----
  {
    const size_t xoff = (size_t)blockIdx.x * 1280;
    for (int i = tid; i < 1280; i += 256) {
      int mm = i / 40, r = i - mm * 40;
      float v = (xoff + i < (size_t)B * 40) ? x[xoff + i] : 0.0f;
      Xs[mm][r] = v;
    }
  }

  // ---- encoder weights: A frags (single f16 RNE, f-pack, SCALED) ----
  half8v eA[4][2];
  float4v ebs[4], eWa[4], eWb[4];
#pragma unroll
  for (int gi = 0; gi < 4; ++gi) {
    const float gsc = (gi == 2) ? TWO_LOG2E : -LOG2E;
    const int nA = m + 16 * (4 * gi + w);
#pragma unroll
    for (int q = 0; q < 2; ++q) {
      const float* wp = &eWhh[nA * 64 + 32 * q + 8 * tg];
      float4v w0 = *(const float4v*)wp;
      float4v w1 = *(const float4v*)(wp + 4);
      half8v hi;
#pragma unroll
      for (int e = 0; e < 4; ++e) {
        hi[e]     = (_Float16)(w0[e] * gsc);
        hi[4 + e] = (_Float16)(w1[e] * gsc);
      }
      eA[gi][q] = hi;
    }
#pragma unroll
    for (int r = 0; r < 4; ++r) {
      const int n = 64 * gi + 16 * w + 4 * tg + r;
      ebs[gi][r] = (ebih[n] + ebhh[n]) * gsc;
      eWa[gi][r] = eWih[n * 2 + 0] * gsc;
      eWb[gi][r] = eWih[n * 2 + 1] * gsc;
    }
  }

  __syncthreads();   // Xs ready

  float4v c0 = {0.f, 0.f, 0.f, 0.f}, c1 = {0.f, 0.f, 0.f, 0.f};
  const half8v z8 = {0, 0, 0, 0, 0, 0, 0, 0};
  half8v b0[2] = {z8, z8}, b1[2] = {z8, z8};
  int p = 0;

  // ---- encoder: 20 steps (tile-sequential: acc0->cell0->acc1->cell1) ----
#pragma unroll 2
  for (int st = 0; st < 20; ++st) {
    short4v hh0, hh1;
    {
      const float xa0 = Xs[m][2 * st], xb0 = Xs[m][2 * st + 1];
      float4v a0[4];
#pragma unroll
      for (int gi = 0; gi < 4; ++gi) {
        float4v i0 = eWa[gi] * xa0 + (eWb[gi] * xb0 + ebs[gi]);   // pk_fma
        float4v a = MFMAH(eA[gi][0], b0[0], i0);
        a0[gi] = MFMAH(eA[gi][1], b0[1], a);
      }
      cellact(a0, c0, hh0);
    }
    {
      const float xa1 = Xs[m + 16][2 * st], xb1 = Xs[m + 16][2 * st + 1];
      float4v a1[4];
#pragma unroll
      for (int gi = 0; gi < 4; ++gi) {
        float4v i1 = eWa[gi] * xa1 + (eWb[gi] * xb1 + ebs[gi]);
        float4v b = MFMAH(eA[gi][0], b1[0], i1);
        a1[gi] = MFMAH(eA[gi][1], b1[1], b);
      }
      cellact(a1, c1, hh1);
    }
    *(short4v*)&Hh[p][m][wslot]      = hh0;
    *(short4v*)&Hh[p][m + 16][wslot] = hh1;
    __syncthreads();
#pragma unroll
    for (int q = 0; q < 2; ++q) {
      const int rs = (((8 * q) | (2 * tg)) ^ msk) << 2;
      b0[q] = *(const half8v*)&Hh[p][m][rs];
      b1[q] = *(const half8v*)&Hh[p][m + 16][rs];
    }
    p ^= 1;
  }

  // ---- decoder weights: Wsum = dWih + dWhh (input == hidden), SCALED ----
  half8v dA[4][2];
  float4v dbsv[4];
#pragma unroll
  for (int gi = 0; gi < 4; ++gi) {
    const float gsc = (gi == 2) ? TWO_LOG2E : -LOG2E;
    const int nA = m + 16 * (4 * gi + w);
#pragma unroll
    for (int q = 0; q < 2; ++q) {
      const float* wpa = &dWih[nA * 64 + 32 * q + 8 * tg];
      const float* wpb = &dWhh[nA * 64 + 32 * q + 8 * tg];
      float4v a0v = *(const float4v*)wpa;
      float4v a1v = *(const float4v*)(wpa + 4);
      float4v b0v = *(const float4v*)wpb;
      float4v b1v = *(const float4v*)(wpb + 4);
      half8v hi;
#pragma unroll
      for (int e = 0; e < 4; ++e) {
        hi[e]     = (_Float16)((a0v[e] + b0v[e]) * gsc);
        hi[4 + e] = (_Float16)((a1v[e] + b1v[e]) * gsc);
      }
      dA[gi][q] = hi;
    }
#pragma unroll
    for (int r = 0; r < 4; ++r) {
      const int n = 64 * gi + 16 * w + 4 * tg + r;
      dbsv[gi][r] = (dbih[n] + dbhh[n]) * gsc;
    }
  }

  // ---- linear-layer A-frag (rows 0,1; single f16 RNE; same f-pack) ----
  half8v LA[2];
#pragma unroll
  for (int q = 0; q < 2; ++q) {
    half8v hi;
#pragma unroll
    for (int e = 0; e < 4; ++e) {
      const int k0 = 32 * q + 8 * tg + e;
      float v0 = (m < 2) ? linW[m * 64 + k0] : 0.0f;
      float v1 = (m < 2) ? linW[m * 64 + k0 + 4] : 0.0f;
      hi[e] = (_Float16)v0;
      hi[4 + e] = (_Float16)v1;
    }
    LA[q] = hi;
  }
  float4v lbinit = {0.f, 0.f, 0.f, 0.f};
  if (tg == 0) { lbinit[0] = linb[0]; lbinit[1] = linb[1]; }

  // ---- decoder: 30 steps (tile-sequential); out[st] via deferred MFMA ----
#pragma unroll 2
  for (int st = 0; st < 30; ++st) {
    short4v hh0, hh1;
    {
      float4v a0[4];
#pragma unroll
      for (int gi = 0; gi < 4; ++gi) {
        float4v a = MFMAH(dA[gi][0], b0[0], dbsv[gi]);
        a0[gi] = MFMAH(dA[gi][1], b0[1], a);
      }
      cellact(a0, c0, hh0);
    }
    {
      float4v a1[4];
#pragma unroll
      for (int gi = 0; gi < 4; ++gi) {
        float4v b = MFMAH(dA[gi][0], b1[0], dbsv[gi]);
        a1[gi] = MFMAH(dA[gi][1], b1[1], b);
      }
      cellact(a1, c1, hh1);
    }
    *(short4v*)&Hh[p][m][wslot]      = hh0;
    *(short4v*)&Hh[p][m + 16][wslot] = hh1;
    __syncthreads();
#pragma unroll
    for (int q = 0; q < 2; ++q) {
      const int rs = (((8 * q) | (2 * tg)) ^ msk) << 2;
      b0[q] = *(const half8v*)&Hh[p][m][rs];
      b1[q] = *(const half8v*)&Hh[p][m + 16][rs];
    }
    // b-frags now hold h_st -> emit out[st] on the matrix pipe.
    if (w == 0) {
      float4v la = lbinit;
      la = MFMAH(LA[0], b0[0], la);
      la = MFMAH(LA[1], b0[1], la);
      if (l < 16 && (bg + l) < B) {
        size_t oidx = ((size_t)(bg + l) * 30 + st) * 2;
        *(float2*)&out[oidx] = make_float2(la[0], la[1]);
      }
    } else if (w == 1) {
      float4v la = lbinit;
      la = MFMAH(LA[0], b1[0], la);
      la = MFMAH(LA[1], b1[1], la);
      if (l < 16 && (bg + 16 + l) < B) {
        size_t oidx = ((size_t)(bg + 16 + l) * 30 + st) * 2;
        *(float2*)&out[oidx] = make_float2(la[0], la[1]);
      }
    }
    p ^= 1;
  }
}

extern "C" void kernel_launch(void* const* d_in, const int* in_sizes, int n_in,
                              void* d_out, int out_size, void* d_ws, size_t ws_size,
                              hipStream_t stream) {
  (void)n_in; (void)out_size; (void)d_ws; (void)ws_size;
  const float* x    = (const float*)d_in[0];
  const float* eWih = (const float*)d_in[1];
  const float* eWhh = (const float*)d_in[2];
  const float* ebih = (const float*)d_in[3];
  const float* ebhh = (const float*)d_in[4];
  const float* dWih = (const float*)d_in[5];
  const float* dWhh = (const float*)d_in[6];
  const float* dbih = (const float*)d_in[7];
  const float* dbhh = (const float*)d_in[8];
  const float* linW = (const float*)d_in[9];
  const float* linb = (const float*)d_in[10];

  const int B = in_sizes[0] / 40;          // [B][20][2]
  const int grid = (B + 31) / 32;          // 32 batch elems per block (2 tiles)
  lstm_fused<<<grid, 256, 0, stream>>>(x, eWih, eWhh, ebih, ebhh,
                                       dWih, dWhh, dbih, dbhh, linW, linb,
                                       (float*)d_out, B);
}

// Round 8
// 432.057 us; speedup vs baseline: 1.0377x; 1.0377x over previous
//
#include <hip/hip_runtime.h>

// LSTM enc(20, in=2) + dec(30, in=h) fused, HID=64, f32 I/O.
// Gates-transposed MFMA recurrence, v_mfma_f32_16x16x32_f16 (K=32).
//   D[n][m] = sum_k W[n][k] h[m][k]; C/D: col=l&15, row=4*(l>>4)+r.
// k-relabeling f(q,tg,e) = 32q+8tg+e on BOTH operands (bijection -> D
// unchanged): A-frag q = 8 contiguous W[n][32q+8tg..+7], B-frag q =
// h[32q+8tg..+7] from identity-layout LDS.  Wave w owns hidden
// [16w,16w+16); h exchanged via dbuf XOR-swizzled Hh, 1 barrier/step.
// TWO batch tiles/block (32 batch).
//
// R8/R9: f16 scheme (f16-RNE h + single f16 W): 16 MFMAs/step,
//   absmax stuck at 2.4e-4 (f16 is not the error floor).
// R10/R11/R12: occupancy hunt.  Measured model: VALU/wave-step ~1046cy
//   (56 trans x 16cy + ~150 full-rate); window = VALU/VALUBusy ->
//   R9 1644 (2 waves), R11 1482 (3 waves, 72%).  FLOOR = 1046cy =
//   ~350us.  Allocator: effective regs = 2x reported (unified-file
//   symmetric): (256,2)->108, (256,3)->84, (256,4)->64.  R11/12 spill
//   ~300MB scratch at 84.  Arch demand must STRUCTURALLY drop to <=80.
// R13 (this round): evict the two register hogs.
//  (1) W A-frags -> LDS WL[10][256][8] f16 (40KB): per-gi-per-tile
//      ds_read_b128 (8-reg transient vs 32 persistent).  Lane-contiguous
//      16B -> conflict-free.  Enc/dec repack WL at the transition (legal:
//      all WL reads precede the step-19 barrier).  LA in slots 8,9.
//  (2) encoder x-projection (eWa/eWb/ebs = 48 regs + 32 pk-fma) -> a
//      THIRD MFMA: logical K in [64,96), A-frag q2 = [Wa,Wb,bias]*gsc
//      (tg=0 lanes; 16 regs), B-frag q2 = [xa,xb,1] f16 from one packed
//      dword (Xs16).  Bias enters in f16 (~3e-4 gate noise, in budget).
//      C-init becomes zero.  +8 MFMA/step on the 21%-busy matrix pipe.
//  LDS 51.8KB/block (x3 = 155 <= 160).  No unroll (pressure).
//  Predict: FETCH ~12k KB (scratch gone), rocprof 493 -> 380-440,
//  VALU 72->85+.  Risk: 24 ds-ops/step ~ 85-90% LDS pipe at floor.

#define LOG2E 1.44269504088896340736f
#define TWO_LOG2E 2.88539008177792681472f

typedef __attribute__((ext_vector_type(4))) short short4v;
typedef __attribute__((ext_vector_type(4))) float float4v;
typedef __attribute__((ext_vector_type(4))) unsigned int uint4v;
typedef _Float16 __attribute__((ext_vector_type(8))) half8v;

#if defined(__HIP_DEVICE_COMPILE__)
#define MFMAH(a, b, c) __builtin_amdgcn_mfma_f32_16x16x32_f16((a), (b), (c), 0, 0, 0)
#else
#define MFMAH(a, b, c) (c)
#endif

__device__ __forceinline__ float4v exp2v4(float4v x) {
  float4v r;
  r[0] = __builtin_amdgcn_exp2f(x[0]);
  r[1] = __builtin_amdgcn_exp2f(x[1]);
  r[2] = __builtin_amdgcn_exp2f(x[2]);
  r[3] = __builtin_amdgcn_exp2f(x[3]);
  return r;
}
__device__ __forceinline__ float4v rcpv4(float4v x) {
  float4v r;
  r[0] = __builtin_amdgcn_rcpf(x[0]);
  r[1] = __builtin_amdgcn_rcpf(x[1]);
  r[2] = __builtin_amdgcn_rcpf(x[2]);
  r[3] = __builtin_amdgcn_rcpf(x[3]);
  return r;
}

// Fused LSTM cell update on 4 rows (pk-f32).  a[0..3] = gates i,f,g,o
// PRE-SCALED (i,f,o by -log2e; g by 2log2e).  c holds 2log2e*cell.
__device__ __forceinline__ void cellact(const float4v* a, float4v& c,
                                        short4v& hh) {
  const float4v one = {1.f, 1.f, 1.f, 1.f};
  const float4v clo = {-36.f, -36.f, -36.f, -36.f};
  const float4v chi = {36.f, 36.f, 36.f, 36.f};
  float4v Ei = exp2v4(a[0]);                    // e^{-i}
  float4v Ef = exp2v4(a[1]);                    // e^{-f}
  float4v Eg = exp2v4(a[2]);                    // e^{2g}
  float4v Eo = exp2v4(a[3]);                    // e^{-o}
  float4v t1 = one + Ei;
  float4v t2 = one + Eg;
  float4v t3 = one + Ef;
  float4v t4s = Eg * TWO_LOG2E - TWO_LOG2E;     // 2log2e*(Eg-1)
  float4v P = t1 * t2;
  float4v num = c * P + t4s * t3;
  float4v cs = num * rcpv4(P * t3);             // 2log2e * c_new
  c = cs;
  float4v cl = __builtin_elementwise_min(__builtin_elementwise_max(cs, clo), chi);
  float4v Ec = exp2v4(cl);
  float4v h = (Ec - one) * rcpv4((one + Ec) * (one + Eo));
#pragma unroll
  for (int r = 0; r < 4; ++r) {
    _Float16 hf = (_Float16)h[r];               // v_cvt_f16_f32 (RNE)
    hh[r] = (short)__builtin_bit_cast(unsigned short, hf);
  }
}

__global__ __launch_bounds__(256, 3) void lstm_fused(
    const float* __restrict__ x,     // [B][20][2]
    const float* __restrict__ eWih,  // [256][2]
    const float* __restrict__ eWhh,  // [256][64]
    const float* __restrict__ ebih,  // [256]
    const float* __restrict__ ebhh,  // [256]
    const float* __restrict__ dWih,  // [256][64]
    const float* __restrict__ dWhh,  // [256][64]
    const float* __restrict__ dbih,  // [256]
    const float* __restrict__ dbhh,  // [256]
    const float* __restrict__ linW,  // [2][64]
    const float* __restrict__ linb,  // [2]
    float* __restrict__ out,         // [B][30][2]
    int B) {
  const int tid = threadIdx.x;
  const int w   = tid >> 6;    // wave: hidden block [16w, 16w+16)
  const int l   = tid & 63;
  const int m   = l & 15;      // batch col within tile
  const int tg  = l >> 4;
  const int msk = m & 14;
  const int wslot = (((w << 2) | tg) ^ msk) << 2;   // halfword off, b64 write
  const int bg  = blockIdx.x * 32;

  __shared__ __align__(16) unsigned short WL[10][256][8];  // W/LA frags, f16
  __shared__ __align__(16) unsigned short Hh[2][32][64];   // h, f16 bits
  __shared__ unsigned int Xs16[32][21];                    // packed f16 x

  const half8v hz8 = {0, 0, 0, 0, 0, 0, 0, 0};
  const float4v zf = {0.f, 0.f, 0.f, 0.f};

  // ---- stage x as packed f16 pairs: Xs16[mm][st] = (xb|xa) ----
  {
    const size_t xoff = (size_t)blockIdx.x * 1280;
    for (int i = tid; i < 640; i += 256) {
      int mm = i / 20, st = i - mm * 20;
      size_t g = xoff + (size_t)mm * 40 + st * 2;
      float xa = 0.f, xb = 0.f;
      if (g + 1 < (size_t)B * 40) { xa = x[g]; xb = x[g + 1]; }
      unsigned ua = __builtin_bit_cast(unsigned short, (_Float16)xa);
      unsigned ub = __builtin_bit_cast(unsigned short, (_Float16)xb);
      Xs16[mm][st] = (ub << 16) | ua;
    }
  }

  // ---- encoder weights: Whh frags -> WL[0..7]; x/bias frag q2 in regs ----
  half8v eA2[4];
#pragma unroll
  for (int gi = 0; gi < 4; ++gi) {
    const float gsc = (gi == 2) ? TWO_LOG2E : -LOG2E;
    const int nA = m + 16 * (4 * gi + w);
#pragma unroll
    for (int q = 0; q < 2; ++q) {
      const float* wp = &eWhh[nA * 64 + 32 * q + 8 * tg];
      float4v w0 = *(const float4v*)wp;
      float4v w1 = *(const float4v*)(wp + 4);
      half8v hi;
#pragma unroll
      for (int e = 0; e < 4; ++e) {
        hi[e]     = (_Float16)(w0[e] * gsc);
        hi[4 + e] = (_Float16)(w1[e] * gsc);
      }
      *(half8v*)&WL[gi * 2 + q][tid][0] = hi;
    }
    half8v a2 = hz8;
    if (tg == 0) {
      a2[0] = (_Float16)(eWih[nA * 2 + 0] * gsc);
      a2[1] = (_Float16)(eWih[nA * 2 + 1] * gsc);
      a2[2] = (_Float16)((ebih[nA] + ebhh[nA]) * gsc);
    }
    eA2[gi] = a2;
  }

  __syncthreads();   // Xs16 + WL ready

  float4v c0 = {0.f, 0.f, 0.f, 0.f}, c1 = {0.f, 0.f, 0.f, 0.f};
  half8v b0[2] = {hz8, hz8}, b1[2] = {hz8, hz8};
  int p = 0;

  // ---- encoder: 20 steps (tile-sequential; frags re-read per tile) ----
#pragma unroll 1
  for (int st = 0; st < 20; ++st) {
    short4v hh0, hh1;
    {
      uint4v t; t[0] = Xs16[m][st]; t[1] = 0x3C00u; t[2] = 0u; t[3] = 0u;
      half8v bq2 = (tg == 0) ? __builtin_bit_cast(half8v, t) : hz8;
      float4v a0[4];
#pragma unroll
      for (int gi = 0; gi < 4; ++gi) {
        half8v f0 = *(const half8v*)&WL[gi * 2 + 0][tid][0];
        half8v f1 = *(const half8v*)&WL[gi * 2 + 1][tid][0];
        float4v a = MFMAH(eA2[gi], bq2, zf);
        a = MFMAH(f0, b0[0], a);
        a0[gi] = MFMAH(f1, b0[1], a);
      }
      cellact(a0, c0, hh0);
    }
    {
      uint4v t; t[0] = Xs16[m + 16][st]; t[1] = 0x3C00u; t[2] = 0u; t[3] = 0u;
      half8v bq2 = (tg == 0) ? __builtin_bit_cast(half8v, t) : hz8;
      float4v a1[4];
#pragma unroll
      for (int gi = 0; gi < 4; ++gi) {
        half8v f0 = *(const half8v*)&WL[gi * 2 + 0][tid][0];
        half8v f1 = *(const half8v*)&WL[gi * 2 + 1][tid][0];
        float4v a = MFMAH(eA2[gi], bq2, zf);
        a = MFMAH(f0, b1[0], a);
        a1[gi] = MFMAH(f1, b1[1], a);
      }
      cellact(a1, c1, hh1);
    }
    *(short4v*)&Hh[p][m][wslot]      = hh0;
    *(short4v*)&Hh[p][m + 16][wslot] = hh1;
    __syncthreads();
#pragma unroll
    for (int q = 0; q < 2; ++q) {
      const int rs = (((8 * q) | (2 * tg)) ^ msk) << 2;
      b0[q] = *(const half8v*)&Hh[p][m][rs];
      b1[q] = *(const half8v*)&Hh[p][m + 16][rs];
    }
    p ^= 1;
  }

  // ---- transition: repack WL with decoder Wsum + LA; dbsv in regs ----
  // (legal: every encoder WL read precedes the step-19 barrier)
  float4v dbsv[4];
#pragma unroll
  for (int gi = 0; gi < 4; ++gi) {
    const float gsc = (gi == 2) ? TWO_LOG2E : -LOG2E;
    const int nA = m + 16 * (4 * gi + w);
#pragma unroll
    for (int q = 0; q < 2; ++q) {
      const float* wpa = &dWih[nA * 64 + 32 * q + 8 * tg];
      const float* wpb = &dWhh[nA * 64 + 32 * q + 8 * tg];
      float4v a0v = *(const float4v*)wpa;
      float4v a1v = *(const float4v*)(wpa + 4);
      float4v b0v = *(const float4v*)wpb;
      float4v b1v = *(const float4v*)(wpb + 4);
      half8v hi;
#pragma unroll
      for (int e = 0; e < 4; ++e) {
        hi[e]     = (_Float16)((a0v[e] + b0v[e]) * gsc);
        hi[4 + e] = (_Float16)((a1v[e] + b1v[e]) * gsc);
      }
      *(half8v*)&WL[gi * 2 + q][tid][0] = hi;
    }
#pragma unroll
    for (int r = 0; r < 4; ++r) {
      const int n = 64 * gi + 16 * w + 4 * tg + r;
      dbsv[gi][r] = (dbih[n] + dbhh[n]) * gsc;
    }
  }
#pragma unroll
  for (int q = 0; q < 2; ++q) {
    half8v hi = hz8;
    if (m < 2) {
      const int k0 = 32 * q + 8 * tg;
#pragma unroll
      for (int e = 0; e < 4; ++e) {
        hi[e]     = (_Float16)linW[m * 64 + k0 + e];
        hi[4 + e] = (_Float16)linW[m * 64 + k0 + e + 4];
      }
    }
    *(half8v*)&WL[8 + q][tid][0] = hi;
  }
  float4v lbinit = {0.f, 0.f, 0.f, 0.f};
  if (tg == 0) { lbinit[0] = linb[0]; lbinit[1] = linb[1]; }
  __syncthreads();   // decoder WL ready

  // ---- decoder: 30 steps; out[st] emitted via MFMA after the exchange ----
#pragma unroll 1
  for (int st = 0; st < 30; ++st) {
    short4v hh0, hh1;
    {
      float4v a0[4];
#pragma unroll
      for (int gi = 0; gi < 4; ++gi) {
        half8v f0 = *(const half8v*)&WL[gi * 2 + 0][tid][0];
        half8v f1 = *(const half8v*)&WL[gi * 2 + 1][tid][0];
        float4v a = MFMAH(f0, b0[0], dbsv[gi]);
        a0[gi] = MFMAH(f1, b0[1], a);
      }
      cellact(a0, c0, hh0);
    }
    {
      float4v a1[4];
#pragma unroll
      for (int gi = 0; gi < 4; ++gi) {
        half8v f0 = *(const half8v*)&WL[gi * 2 + 0][tid][0];
        half8v f1 = *(const half8v*)&WL[gi * 2 + 1][tid][0];
        float4v a = MFMAH(f0, b1[0], dbsv[gi]);
        a1[gi] = MFMAH(f1, b1[1], a);
      }
      cellact(a1, c1, hh1);
    }
    *(short4v*)&Hh[p][m][wslot]      = hh0;
    *(short4v*)&Hh[p][m + 16][wslot] = hh1;
    __syncthreads();
#pragma unroll
    for (int q = 0; q < 2; ++q) {
      const int rs = (((8 * q) | (2 * tg)) ^ msk) << 2;
      b0[q] = *(const half8v*)&Hh[p][m][rs];
      b1[q] = *(const half8v*)&Hh[p][m + 16][rs];
    }
    // b-frags now hold h_st -> emit out[st] on the matrix pipe.
    if (w == 0) {
      half8v L0 = *(const half8v*)&WL[8][tid][0];
      half8v L1 = *(const half8v*)&WL[9][tid][0];
      float4v la = lbinit;
      la = MFMAH(L0, b0[0], la);
      la = MFMAH(L1, b0[1], la);
      if (l < 16 && (bg + l) < B) {
        size_t oidx = ((size_t)(bg + l) * 30 + st) * 2;
        *(float2*)&out[oidx] = make_float2(la[0], la[1]);
      }
    } else if (w == 1) {
      half8v L0 = *(const half8v*)&WL[8][tid][0];
      half8v L1 = *(const half8v*)&WL[9][tid][0];
      float4v la = lbinit;
      la = MFMAH(L0, b1[0], la);
      la = MFMAH(L1, b1[1], la);
      if (l < 16 && (bg + 16 + l) < B) {
        size_t oidx = ((size_t)(bg + 16 + l) * 30 + st) * 2;
        *(float2*)&out[oidx] = make_float2(la[0], la[1]);
      }
    }
    p ^= 1;
  }
}

extern "C" void kernel_launch(void* const* d_in, const int* in_sizes, int n_in,
                              void* d_out, int out_size, void* d_ws, size_t ws_size,
                              hipStream_t stream) {
  (void)n_in; (void)out_size; (void)d_ws; (void)ws_size;
  const float* x    = (const float*)d_in[0];
  const float* eWih = (const float*)d_in[1];
  const float* eWhh = (const float*)d_in[2];
  const float* ebih = (const float*)d_in[3];
  const float* ebhh = (const float*)d_in[4];
  const float* dWih = (const float*)d_in[5];
  const float* dWhh = (const float*)d_in[6];
  const float* dbih = (const float*)d_in[7];
  const float* dbhh = (const float*)d_in[8];
  const float* linW = (const float*)d_in[9];
  const float* linb = (const float*)d_in[10];

  const int B = in_sizes[0] / 40;          // [B][20][2]
  const int grid = (B + 31) / 32;          // 32 batch elems per block (2 tiles)
  lstm_fused<<<grid, 256, 0, stream>>>(x, eWih, eWhh, ebih, ebhh,
                                       dWih, dWhh, dbih, dbhh, linW, linb,
                                       (float*)d_out, B);
}